// Round 12
// baseline (184.710 us; speedup 1.0000x reference)
//
#include <hip/hip_runtime.h>

typedef unsigned short u16;
typedef unsigned int u32;
typedef __attribute__((ext_vector_type(8))) short s16x8;
typedef __attribute__((ext_vector_type(4))) float f32x4;

#define DEV __device__ __forceinline__
#define MFMA16(a,b,c) __builtin_amdgcn_mfma_f32_16x16x32_bf16(a,b,c,0,0,0)

DEV float bf2f(u16 x){ u32 u=((u32)x)<<16; float f; __builtin_memcpy(&f,&u,4); return f; }
DEV u16 f2bf(float f){ u32 u; __builtin_memcpy(&u,&f,4); u32 r=u+0x7FFFu+((u>>16)&1u); return (u16)(r>>16); }
DEV uint4 pack8(const float* f){
  uint4 v;
  v.x=(u32)f2bf(f[0])|((u32)f2bf(f[1])<<16);
  v.y=(u32)f2bf(f[2])|((u32)f2bf(f[3])<<16);
  v.z=(u32)f2bf(f[4])|((u32)f2bf(f[5])<<16);
  v.w=(u32)f2bf(f[6])|((u32)f2bf(f[7])<<16);
  return v;
}
DEV float sigm(float x){ return 1.0f/(1.0f+__expf(-x)); }

// Fragment layout for s1/s2 (=w1c/w2c): addr(col,k) =
//   (col>>4)*2048 + (k>>5)*512 + ((k>>3)&3)*128 + (col&15)*8 + (k&7)

// ---------------------------------------------------------------------------
// act-guarded transpose tile: dst[n][k] = bf16(src[k][n]), 64x64, 256 active thr
// ---------------------------------------------------------------------------
DEV void trans_tile_a(const float* src, u16* dst, int K, int Nn, int bx, int by,
                      int tid, bool act, float* ld)
{
  int n0 = bx*64, k0 = by*64;
  if (act){
    #pragma unroll
    for (int rr=0; rr<4; rr++){
      int kk = rr*16 + (tid>>4);
      int nn = (tid&15)*4;
      float4 v = *(const float4*)(src + (size_t)(k0+kk)*Nn + n0 + nn);
      ld[kk*65+nn]=v.x; ld[kk*65+nn+1]=v.y; ld[kk*65+nn+2]=v.z; ld[kk*65+nn+3]=v.w;
    }
  }
  __syncthreads();
  if (act){
    int nn2 = tid>>2, kb = (tid&3)*16;
    float o[16];
    #pragma unroll
    for (int j=0;j<16;j++) o[j] = ld[(kb+j)*65+nn2];
    u16* dp = dst + (size_t)(n0+nn2)*K + k0 + kb;
    *(uint4*)dp     = pack8(&o[0]);
    *(uint4*)(dp+8) = pack8(&o[8]);
  }
}

// ---------------------------------------------------------------------------
// K_front: blocks [0,256) token rmsnorm + chunk gates; [256,528) weight prep.
// ---------------------------------------------------------------------------
__global__ __launch_bounds__(512) void k_front(const float* __restrict__ seq,
    const float* __restrict__ gs, const float* __restrict__ gr,
    const float* __restrict__ Wstep, const float* __restrict__ Wgate,
    const float* __restrict__ Wdec, const float* __restrict__ Wmom,
    const float* __restrict__ Wkv, const float* __restrict__ Wq,
    const float* __restrict__ Wo, const float* __restrict__ MW1,
    const float* __restrict__ MW2,
    u16* __restrict__ s, u16* __restrict__ r,
    float* __restrict__ lr, float* __restrict__ gate,
    float* __restrict__ momv, float* __restrict__ dgv,
    u16* __restrict__ Wkvt, u16* __restrict__ Wqt, u16* __restrict__ Wot,
    u16* __restrict__ W1t, u16* __restrict__ W2t, u16* __restrict__ W2s)
{
  __shared__ float smem[8192];
  const int blk = blockIdx.x;
  const int tid = threadIdx.x;

  if (blk >= 256){
    int l = blk - 256;
    bool act = tid < 256;
    int t2 = tid & 255;
    if (l < 128)      trans_tile_a(Wkv, Wkvt, 512, 1024, l&15, l>>4, t2, act, smem);
    else if (l < 192){ int m = l-128; trans_tile_a(Wq, Wqt, 512, 512, m&7, m>>3, t2, act, smem); }
    else if (l < 256){ int m = l-192; trans_tile_a(Wo, Wot, 512, 512, m&7, m>>3, t2, act, smem); }
    else if (l < 260){ int m = l-256; trans_tile_a(MW1, W1t, 128, 128, m&1, m>>1, t2, act, smem); }
    else if (l < 264){ int m = l-260; trans_tile_a(MW2, W2t, 128, 128, m&1, m>>1, t2, act, smem); }
    else {
      __syncthreads();
      if (act){
        int e = ((l-264)*256 + t2)*8;
        float f[8];
        *(float4*)&f[0] = *(const float4*)(MW2+e);
        *(float4*)&f[4] = *(const float4*)(MW2+e+4);
        *(uint4*)(W2s+e) = pack8(f);
      }
    }
    return;
  }

  float* pchunk = smem;
  float* red    = smem + 4096;
  const int b = blk >> 6, ci = blk & 63;
  const int wv = tid >> 6, lane = tid & 63;
  const size_t rowbase = (size_t)b*4096 + (size_t)ci*64;

  float psum[8] = {0,0,0,0,0,0,0,0};
  #pragma unroll 1
  for (int tt=0; tt<8; tt++){
    int t = wv*8 + tt;
    const float* row = seq + (rowbase + t)*512;
    float x[8];
    *(float4*)&x[0] = *(const float4*)(row + lane*8);
    *(float4*)&x[4] = *(const float4*)(row + lane*8 + 4);
    float ss = 0.f;
    #pragma unroll
    for (int j=0;j<8;j++) ss += x[j]*x[j];
    #pragma unroll
    for (int o=32;o>=1;o>>=1) ss += __shfl_xor(ss, o, 64);
    float inv = rsqrtf(ss*(1.0f/512.0f) + 1e-6f);
    float al[4] = {0,0,0,0}, ag[4] = {0,0,0,0};
    float sv8[8], rv8[8];
    #pragma unroll
    for (int j=0;j<8;j++){
      int d = lane*8 + j;
      float sn = x[j]*inv;
      float sv = sn*gs[d];
      float rv = sn*gr[d];
      sv8[j]=sv; rv8[j]=rv;
      psum[j] += sv;
      float4 wst = *(const float4*)(Wstep + d*4);
      float4 wgt = *(const float4*)(Wgate + d*4);
      al[0]+=sv*wst.x; al[1]+=sv*wst.y; al[2]+=sv*wst.z; al[3]+=sv*wst.w;
      ag[0]+=rv*wgt.x; ag[1]+=rv*wgt.y; ag[2]+=rv*wgt.z; ag[3]+=rv*wgt.w;
    }
    *(uint4*)(s + (rowbase+t)*512 + lane*8) = pack8(sv8);
    *(uint4*)(r + (rowbase+t)*512 + lane*8) = pack8(rv8);
    #pragma unroll
    for (int o=32;o>=1;o>>=1){
      #pragma unroll
      for (int h=0;h<4;h++){ al[h] += __shfl_xor(al[h], o, 64); ag[h] += __shfl_xor(ag[h], o, 64); }
    }
    if (lane == 0){
      #pragma unroll
      for (int h=0;h<4;h++){
        lr[(rowbase+t)*4 + h]   = sigm(al[h]);
        gate[(rowbase+t)*4 + h] = sigm(ag[h]);
      }
    }
  }
  #pragma unroll
  for (int j=0;j<8;j++) pchunk[wv*512 + lane*8+j] = psum[j];
  __syncthreads();
  {
    int d = tid;
    float mean = 0.f;
    #pragma unroll
    for (int w=0;w<8;w++) mean += pchunk[w*512 + d];
    mean *= (1.0f/64.0f);
    #pragma unroll
    for (int h=0;h<4;h++){
      red[h*512 + d]     = mean*Wdec[d*4+h];
      red[(4+h)*512 + d] = mean*Wmom[d*4+h];
    }
  }
  __syncthreads();
  {
    float sum = 0.f;
    #pragma unroll
    for (int j=0;j<8;j++) sum += red[wv*512 + lane*8+j];
    #pragma unroll
    for (int o=32;o>=1;o>>=1) sum += __shfl_xor(sum, o, 64);
    if (lane == 0){
      if (wv < 4) dgv[((size_t)(b*4+wv))*64 + ci]      = 1.0f - sigm(sum);
      else        momv[((size_t)(b*4+(wv-4)))*64 + ci] = sigm(sum);
    }
  }
}

// ---------------------------------------------------------------------------
// GEMM tile body (m97 structure).
// ---------------------------------------------------------------------------
template<bool OUT_BF>
DEV void gemm_body(const u16* A, const u16* Bt, void* Cv, int K, int ldc,
                   int bx, int by, u16* sA, u16* sB)
{
  const int tid = threadIdx.x;
  const int wv = tid>>6, lane = tid&63, lrow = lane&15, lk = lane>>4;
  const int wm = (wv>>1)*64, wn = (wv&1)*64;
  const int rowbase = by*128, colbase = bx*128;
  const int srow = lane>>3;
  const int scol = (lane&7)*8;
  f32x4 acc[4][4] = {};
  for (int kc = 0; kc < K; kc += 64){
    __syncthreads();
    #pragma unroll
    for (int it=0; it<4; ++it){
      int seg = it*4 + wv;
      int row = seg*8 + srow;
      __builtin_amdgcn_global_load_lds(
        (const __attribute__((address_space(1))) void*)(A + (size_t)(rowbase+row)*K + kc + scol),
        (__attribute__((address_space(3))) void*)&sA[seg*512 + lane*8], 16, 0, 0);
      __builtin_amdgcn_global_load_lds(
        (const __attribute__((address_space(1))) void*)(Bt + (size_t)(colbase+row)*K + kc + scol),
        (__attribute__((address_space(3))) void*)&sB[seg*512 + lane*8], 16, 0, 0);
    }
    __syncthreads();
    #pragma unroll
    for (int k0=0;k0<2;k0++){
      s16x8 a[4], b[4];
      #pragma unroll
      for (int m=0;m<4;m++) a[m] = *(const s16x8*)&sA[(wm+m*16+lrow)*64 + k0*32 + lk*8];
      #pragma unroll
      for (int n=0;n<4;n++) b[n] = *(const s16x8*)&sB[(wn+n*16+lrow)*64 + k0*32 + lk*8];
      #pragma unroll
      for (int m=0;m<4;m++)
        #pragma unroll
        for (int n=0;n<4;n++)
          acc[m][n] = MFMA16(a[m], b[n], acc[m][n]);
    }
  }
  #pragma unroll
  for (int m=0;m<4;m++)
    #pragma unroll
    for (int n=0;n<4;n++)
      #pragma unroll
      for (int r=0;r<4;r++){
        int row = rowbase + wm + m*16 + lk*4 + r;
        int col = colbase + wn + n*16 + lrow;
        float v = acc[m][n][r];
        if (OUT_BF) ((u16*)Cv)[(size_t)row*ldc + col] = f2bf(v);
        else        ((float*)Cv)[(size_t)row*ldc + col] = v;
      }
}

// merged kv + q GEMM
__global__ __launch_bounds__(256) void k_gemmAB(const u16* __restrict__ A1,
    const u16* __restrict__ B1, u16* __restrict__ C1,
    const u16* __restrict__ A2, const u16* __restrict__ B2, u16* __restrict__ C2)
{
  __shared__ u16 sA[128*64];
  __shared__ u16 sB[128*64];
  int bid = blockIdx.x;
  if (bid < 1024){
    int s = (bid & 7)*128 + (bid >> 3);
    gemm_body<true>(A1, B1, C1, 512, 1024, s & 7, s >> 3, sA, sB);
  } else {
    int l = bid - 1024;
    int s = (l & 7)*64 + (l >> 3);
    gemm_body<true>(A2, B2, C2, 512, 512, s & 3, s >> 2, sA, sB);
  }
}

// single GEMM (out-projection)
template<bool OUT_BF>
__global__ __launch_bounds__(256) void k_gemm1(const u16* __restrict__ A,
    const u16* __restrict__ Bt, void* __restrict__ Cv, int K, int ldc, int nbx, int cpx)
{
  __shared__ u16 sA[128*64];
  __shared__ u16 sB[128*64];
  int bid = blockIdx.x;
  int s = (bid & 7)*cpx + (bid >> 3);
  gemm_body<OUT_BF>(A, Bt, Cv, K, ldc, s % nbx, s / nbx, sA, sB);
}

// ---------------------------------------------------------------------------
// K4: per-chunk gradient, 2 chunks per block with buffer-role rotation.
// Chunk parity p: R = kc->As->dP->dHt chain, T = Ast, V = v->dPt.
// Next chunk's kc/v staged into T,V during mm5 (same barrier region).
// ---------------------------------------------------------------------------
__global__ __launch_bounds__(256,4) void k_grad(const u16* __restrict__ kv,
    const float* __restrict__ lr, const u16* __restrict__ W1t,
    const u16* __restrict__ W2t, const u16* __restrict__ W2s,
    u16* __restrict__ s1, u16* __restrict__ s2)
{
  __shared__ u16 bufA[64*136];   // 8704 u16, dual-view [64][136] / [128][68]
  __shared__ u16 bufB[64*136];
  __shared__ u16 bufC[64*136];
  __shared__ float lrs[64];

  const int blk = blockIdx.x;
  const int bhi = blk >> 5, cih = blk & 31;
  const int b = bhi >> 2, hd = bhi & 3;
  const int tid = threadIdx.x;
  const int wv = tid>>6, lane = tid&63, lrow = lane&15, lk = lane>>4;
  int col[2]; col[0] = wv*32 + lrow; col[1] = wv*32 + 16 + lrow;
  const int f_hi[2] = { (lrow>>3)*128, ((16+lrow)>>3)*128 };
  const int f_lo[2] = { lrow&7, (16+lrow)&7 };
  const int fbase = wv*512;

  // prologue: stage chunk 0 (kc -> bufA, v -> bufC) + lrs
  {
    const size_t rowbase0 = (size_t)b*4096 + (size_t)(cih*2)*64;
    const u16* kvb0 = kv + rowbase0*1024 + hd*128;
    #pragma unroll 2
    for (int rep=0;rep<4;rep++){
      int lin = rep*2048 + tid*8;
      int i = lin >> 7, d = lin & 127;
      *(uint4*)&bufA[i*136 + d] = *(const uint4*)(kvb0 + (size_t)i*1024 + d);
      *(uint4*)&bufC[i*136 + d] = *(const uint4*)(kvb0 + (size_t)i*1024 + 512 + d);
    }
    if (tid < 64) lrs[tid] = lr[(rowbase0 + tid)*4 + hd] * (2.0f/128.0f);
  }

  #pragma unroll 1
  for (int p=0; p<2; p++){
    u16* R = p ? bufB : bufA;
    u16* T = p ? bufA : bufB;
    u16* V = bufC;
    const int chunk = cih*2 + p;
    const size_t rowbase = (size_t)b*4096 + (size_t)chunk*64;
    const u16* kvb = kv + rowbase*1024 + hd*128;
    const size_t outbase = (size_t)(bhi*64 + chunk) * 16384;

    __syncthreads();   // A: stage complete / prev chunk fully done

    float spv[4][2][4];

    // mm1: H = kc @ W1 ; A = silu(H)
    {
      f32x4 acc[4][2] = {};
      #pragma unroll
      for (int k0=0;k0<4;k0++){
        s16x8 w0 = *(const s16x8*)(W1t + col[0]*128 + k0*32 + lk*8);
        s16x8 w1 = *(const s16x8*)(W1t + col[1]*128 + k0*32 + lk*8);
        #pragma unroll
        for (int m=0;m<4;m++){
          s16x8 a = *(const s16x8*)&R[(m*16+lrow)*136 + k0*32 + lk*8];
          acc[m][0] = MFMA16(a, w0, acc[m][0]);
          acc[m][1] = MFMA16(a, w1, acc[m][1]);
        }
      }
      __syncthreads();  // B: kc reads complete
      #pragma unroll
      for (int m=0;m<4;m++)
        #pragma unroll
        for (int n=0;n<2;n++){
          int row0 = m*16 + lk*4;
          u16 av4[4];
          #pragma unroll
          for (int r=0;r<4;r++){
            float h = acc[m][n][r];
            float sg = sigm(h);
            av4[r] = f2bf(h*sg);
            spv[m][n][r] = sg*(1.0f + h*(1.0f - sg));
            R[(row0+r)*136 + col[n]] = av4[r];
          }
          *(uint2*)&T[col[n]*68 + row0] = make_uint2(
            (u32)av4[0] | ((u32)av4[1]<<16), (u32)av4[2] | ((u32)av4[3]<<16));
        }
    }
    __syncthreads();    // C

    // mm2: P = A @ W2 ; dP = lr*(P - v)  (v from V [64][136] view)
    {
      f32x4 acc[4][2] = {};
      #pragma unroll
      for (int k0=0;k0<4;k0++){
        s16x8 w0 = *(const s16x8*)(W2t + col[0]*128 + k0*32 + lk*8);
        s16x8 w1 = *(const s16x8*)(W2t + col[1]*128 + k0*32 + lk*8);
        #pragma unroll
        for (int m=0;m<4;m++){
          s16x8 a = *(const s16x8*)&R[(m*16+lrow)*136 + k0*32 + lk*8];
          acc[m][0] = MFMA16(a, w0, acc[m][0]);
          acc[m][1] = MFMA16(a, w1, acc[m][1]);
        }
      }
      u16 vv[4][2][4];
      #pragma unroll
      for (int m=0;m<4;m++)
        #pragma unroll
        for (int n=0;n<2;n++)
          #pragma unroll
          for (int r=0;r<4;r++)
            vv[m][n][r] = V[(m*16+lk*4+r)*136 + col[n]];
      __syncthreads();  // D: As reads + v reads complete
      #pragma unroll
      for (int m=0;m<4;m++)
        #pragma unroll
        for (int n=0;n<2;n++){
          int row0 = m*16 + lk*4;
          u16 dp4[4];
          #pragma unroll
          for (int r=0;r<4;r++){
            float dp = lrs[row0+r]*(acc[m][n][r] - bf2f(vv[m][n][r]));
            dp4[r] = f2bf(dp);
            R[(row0+r)*136 + col[n]] = dp4[r];
          }
          *(uint2*)&V[col[n]*68 + row0] = make_uint2(
            (u32)dp4[0] | ((u32)dp4[1]<<16), (u32)dp4[2] | ((u32)dp4[3]<<16));
        }
    }
    __syncthreads();    // E

    // mm3: dA = dP @ W2^T ; dHt -> R ([128][68] view)
    {
      f32x4 da[4][2] = {};
      #pragma unroll
      for (int k0=0;k0<4;k0++){
        s16x8 w0 = *(const s16x8*)(W2s + col[0]*128 + k0*32 + lk*8);
        s16x8 w1 = *(const s16x8*)(W2s + col[1]*128 + k0*32 + lk*8);
        #pragma unroll
        for (int m=0;m<4;m++){
          s16x8 a = *(const s16x8*)&R[(m*16+lrow)*136 + k0*32 + lk*8];
          da[m][0] = MFMA16(a, w0, da[m][0]);
          da[m][1] = MFMA16(a, w1, da[m][1]);
        }
      }
      __syncthreads();  // dP reads complete; R free
      #pragma unroll
      for (int m=0;m<4;m++)
        #pragma unroll
        for (int n=0;n<2;n++){
          int row0 = m*16 + lk*4;
          u16 dh4[4];
          #pragma unroll
          for (int r=0;r<4;r++) dh4[r] = f2bf(spv[m][n][r]*da[m][n][r]);
          *(uint2*)&R[col[n]*68 + row0] = make_uint2(
            (u32)dh4[0] | ((u32)dh4[1]<<16), (u32)dh4[2] | ((u32)dh4[3]<<16));
        }
    }

    // mm4: s2 = -(dPt x Ast)  (reads T, V) ; kct gather alongside
    s16x8 kbf[2][2];
    #pragma unroll
    for (int n=0;n<2;n++)
      #pragma unroll
      for (int k0=0;k0<2;k0++)
        #pragma unroll
        for (int j=0;j<8;j++)
          ((u16*)&kbf[n][k0])[j] = kvb[(size_t)(k0*32 + lk*8 + j)*1024 + col[n]];
    {
      f32x4 acc[8][2] = {};
      #pragma unroll
      for (int k0=0;k0<2;k0++){
        s16x8 bf0 = *(const s16x8*)&T[col[0]*68 + k0*32 + lk*8];
        s16x8 bf1 = *(const s16x8*)&T[col[1]*68 + k0*32 + lk*8];
        #pragma unroll
        for (int m=0;m<8;m++){
          s16x8 a = *(const s16x8*)&V[(m*16+lrow)*68 + k0*32 + lk*8];
          acc[m][0] = MFMA16(a, bf0, acc[m][0]);
          acc[m][1] = MFMA16(a, bf1, acc[m][1]);
        }
      }
      #pragma unroll
      for (int m=0;m<8;m++)
        #pragma unroll
        for (int n=0;n<2;n++)
          #pragma unroll
          for (int r=0;r<4;r++)
            s2[outbase + m*2048 + fbase + f_hi[n] + (lk*4+r)*8 + f_lo[n]] = f2bf(-acc[m][n][r]);
    }
    __syncthreads();    // F: dHt visible; T and V dead block-wide

    // stage next chunk (kc -> T, v -> V) overlapped with mm5
    if (p == 0){
      const u16* kvb2 = kvb + (size_t)64*1024;
      #pragma unroll 2
      for (int rep=0;rep<4;rep++){
        int lin = rep*2048 + tid*8;
        int i = lin >> 7, d = lin & 127;
        *(uint4*)&T[i*136 + d] = *(const uint4*)(kvb2 + (size_t)i*1024 + d);
        *(uint4*)&V[i*136 + d] = *(const uint4*)(kvb2 + (size_t)i*1024 + 512 + d);
      }
      if (tid < 64) lrs[tid] = lr[(rowbase + 64 + tid)*4 + hd] * (2.0f/128.0f);
    }

    // mm5: s1 = -(dHt x kct)  (reads R as [128][68]; kct from regs)
    {
      f32x4 acc[8][2] = {};
      #pragma unroll
      for (int k0=0;k0<2;k0++)
        #pragma unroll
        for (int m=0;m<8;m++){
          s16x8 a = *(const s16x8*)&R[(m*16+lrow)*68 + k0*32 + lk*8];
          acc[m][0] = MFMA16(a, kbf[0][k0], acc[m][0]);
          acc[m][1] = MFMA16(a, kbf[1][k0], acc[m][1]);
        }
      #pragma unroll
      for (int m=0;m<8;m++)
        #pragma unroll
        for (int n=0;n<2;n++)
          #pragma unroll
          for (int r=0;r<4;r++)
            s1[outbase + m*2048 + fbase + f_hi[n] + (lk*4+r)*8 + f_lo[n]] = f2bf(-acc[m][n][r]);
    }
  }
}

// ---------------------------------------------------------------------------
// K5: fused momentum + decay scans, 4 elems/thread (uint2 per array), unroll 4.
// ---------------------------------------------------------------------------
__global__ __launch_bounds__(256) void k_scan(const float* __restrict__ momv,
    const float* __restrict__ dgv, const float* __restrict__ MW1,
    const float* __restrict__ MW2, u16* __restrict__ s1w, u16* __restrict__ s2w)
{
  int bhi = blockIdx.x >> 4, eb = blockIdx.x & 15;
  int e0 = eb*1024 + threadIdx.x*4;
  int colD = ((e0>>11)<<4) + ((e0>>3)&15);
  int kD   = ((e0>>9)&3)*32 + ((e0>>7)&3)*8 + (e0&7);
  float u1[4], u2[4], m1[4]={0,0,0,0}, m2[4]={0,0,0,0};
  #pragma unroll
  for (int j=0;j<4;j++){
    u1[j] = MW1[(kD+j)*128 + colD];
    u2[j] = MW2[(kD+j)*128 + colD];
  }
  size_t base = (size_t)bhi*64*16384 + e0;
  const float* mv = momv + bhi*64;
  const float* dv = dgv + bhi*64;
  #pragma unroll 4
  for (int t=0; t<64; t++){
    float g  = mv[t];
    float dg = dv[t];
    size_t idx = base + (size_t)t*16384;
    uint2 a = *(const uint2*)(s1w + idx);
    uint2 c = *(const uint2*)(s2w + idx);
    uint2 w1o, w2o;
    w1o.x = (u32)f2bf(u1[0]) | ((u32)f2bf(u1[1])<<16);
    w1o.y = (u32)f2bf(u1[2]) | ((u32)f2bf(u1[3])<<16);
    w2o.x = (u32)f2bf(u2[0]) | ((u32)f2bf(u2[1])<<16);
    w2o.y = (u32)f2bf(u2[2]) | ((u32)f2bf(u2[3])<<16);
    *(uint2*)(s1w + idx) = w1o;
    *(uint2*)(s2w + idx) = w2o;
    u16 ah[4] = {(u16)(a.x&0xffffu),(u16)(a.x>>16),(u16)(a.y&0xffffu),(u16)(a.y>>16)};
    u16 ch[4] = {(u16)(c.x&0xffffu),(u16)(c.x>>16),(u16)(c.y&0xffffu),(u16)(c.y>>16)};
    #pragma unroll
    for (int j=0;j<4;j++){
      m1[j] = g*m1[j] + bf2f(ah[j]);
      m2[j] = g*m2[j] + bf2f(ch[j]);
      u1[j] = dg*u1[j] + m1[j];
      u2[j] = dg*u2[j] + m2[j];
    }
  }
}

// ---------------------------------------------------------------------------
// K6: retrieval. q staged via LDS; w1c/w2c coalesced fragment-order loads.
// ---------------------------------------------------------------------------
__global__ __launch_bounds__(512) void k_retr(const u16* __restrict__ qin,
    const u16* __restrict__ w1c, const u16* __restrict__ w2c,
    const float* __restrict__ gate, const float* __restrict__ gamma,
    u16* __restrict__ outp)
{
  __shared__ u16 bufQ[64*136];
  __shared__ u16 bufA[64*132];
  __shared__ float rsum[8][64];
  const int blk = blockIdx.x;
  const int bhi = blk >> 6, ci = blk & 63;
  const int b = bhi >> 2, hd = bhi & 3;
  const int tid = threadIdx.x;
  const int wv = tid>>6, lane = tid&63, lrow = lane&15, lk = lane>>4;
  const int colw = wv*16 + lrow;
  const size_t rowbase = (size_t)b*4096 + (size_t)ci*64;
  const u16* w1 = w1c + (size_t)blk*16384;
  const u16* w2 = w2c + (size_t)blk*16384;
  const int lane8 = lane*8;

  #pragma unroll
  for (int rep=0;rep<2;rep++){
    int lin = rep*4096 + tid*8;
    int i = lin>>7, d = lin&127;
    *(uint4*)&bufQ[i*136 + d] = *(const uint4*)(qin + (rowbase+i)*512 + hd*128 + d);
  }
  __syncthreads();

  // mm1: Hq = q @ w1 ; A = silu
  {
    s16x8 wf[4];
    #pragma unroll
    for (int k0=0;k0<4;k0++) wf[k0] = *(const s16x8*)(w1 + wv*2048 + k0*512 + lane8);
    f32x4 acc[4] = {};
    #pragma unroll
    for (int k0=0;k0<4;k0++){
      #pragma unroll
      for (int m=0;m<4;m++){
        s16x8 a = *(const s16x8*)&bufQ[(m*16+lrow)*136 + k0*32 + lk*8];
        acc[m] = MFMA16(a, wf[k0], acc[m]);
      }
    }
    #pragma unroll
    for (int m=0;m<4;m++){
      #pragma unroll
      for (int r=0;r<4;r++){
        float h = acc[m][r];
        bufA[(m*16+lk*4+r)*132 + colw] = f2bf(h*sigm(h));
      }
    }
  }
  __syncthreads();

  // mm2: P = A @ w2
  f32x4 acc[4] = {};
  {
    s16x8 wf[4];
    #pragma unroll
    for (int k0=0;k0<4;k0++) wf[k0] = *(const s16x8*)(w2 + wv*2048 + k0*512 + lane8);
    #pragma unroll
    for (int k0=0;k0<4;k0++){
      #pragma unroll
      for (int m=0;m<4;m++){
        s16x8 a = *(const s16x8*)&bufA[(m*16+lrow)*132 + k0*32 + lk*8];
        acc[m] = MFMA16(a, wf[k0], acc[m]);
      }
    }
  }
  #pragma unroll
  for (int m=0;m<4;m++){
    #pragma unroll
    for (int r=0;r<4;r++){
      float p = acc[m][r]*acc[m][r];
      p += __shfl_xor(p, 1, 64);
      p += __shfl_xor(p, 2, 64);
      p += __shfl_xor(p, 4, 64);
      p += __shfl_xor(p, 8, 64);
      if (lrow == 0) rsum[wv][m*16 + lk*4 + r] = p;
    }
  }
  __syncthreads();
  float gm = gamma[hd*128 + colw] + 1.0f;
  #pragma unroll
  for (int m=0;m<4;m++){
    #pragma unroll
    for (int r=0;r<4;r++){
      int row = m*16 + lk*4 + r;
      float sum = rsum[0][row]+rsum[1][row]+rsum[2][row]+rsum[3][row]
                + rsum[4][row]+rsum[5][row]+rsum[6][row]+rsum[7][row];
      float inv = rsqrtf(sum*(1.0f/128.0f) + 1e-6f);
      float gt = gate[(rowbase+row)*4 + hd];
      outp[(rowbase+row)*512 + hd*128 + colw] = f2bf(acc[m][r]*inv*gm*gt);
    }
  }
}

// ---------------------------------------------------------------------------
extern "C" void kernel_launch(void* const* d_in, const int* in_sizes, int n_in,
                              void* d_out, int out_size, void* d_ws, size_t ws_size,
                              hipStream_t stream)
{
  const float* seq    = (const float*)d_in[0];
  const float* gstore = (const float*)d_in[1];
  const float* gret   = (const float*)d_in[2];
  const float* W_q    = (const float*)d_in[3];
  const float* W_kv   = (const float*)d_in[4];
  const float* W_step = (const float*)d_in[5];
  const float* W_mom  = (const float*)d_in[6];
  const float* W_dec  = (const float*)d_in[7];
  const float* W_gate = (const float*)d_in[8];
  const float* gamma  = (const float*)d_in[9];
  const float* W_o    = (const float*)d_in[10];
  const float* MW1    = (const float*)d_in[11];
  const float* MW2    = (const float*)d_in[12];
  float* out = (float*)d_out;

  const size_t NS = (size_t)16384*512;
  const size_t NG = (size_t)16*64*16384;
  size_t need = (5*NS + 2*NG + 524288 + 262144 + 262144 + 3*16384)*2
              + (2*65536 + 2048)*4;
  if (ws_size < need) return;

  char* ws = (char*)d_ws;
  u16* s_bf = (u16*)ws; ws += NS*2;        // s; reused as outp
  u16* r_bf = (u16*)ws; ws += NS*2;
  u16* kv_bf= (u16*)ws; ws += 2*NS*2;
  u16* q_bf = (u16*)ws; ws += NS*2;
  u16* s1   = (u16*)ws; ws += NG*2;        // -> w1c after k_scan
  u16* s2   = (u16*)ws; ws += NG*2;        // -> w2c
  u16* Wkvt = (u16*)ws; ws += (size_t)524288*2;
  u16* Wqt  = (u16*)ws; ws += (size_t)262144*2;
  u16* Wot  = (u16*)ws; ws += (size_t)262144*2;
  u16* W1tb = (u16*)ws; ws += (size_t)16384*2;
  u16* W2tb = (u16*)ws; ws += (size_t)16384*2;
  u16* W2sb = (u16*)ws; ws += (size_t)16384*2;
  float* lr   = (float*)ws; ws += (size_t)65536*4;
  float* gatep= (float*)ws; ws += (size_t)65536*4;
  float* momv = (float*)ws; ws += 1024*4;
  float* dgv  = (float*)ws; ws += 1024*4;
  u16* outp = s_bf;

  k_front<<<528, 512, 0, stream>>>(seq, gstore, gret, W_step, W_gate, W_dec, W_mom,
                                   W_kv, W_q, W_o, MW1, MW2,
                                   s_bf, r_bf, lr, gatep, momv, dgv,
                                   Wkvt, Wqt, Wot, W1tb, W2tb, W2sb);
  k_gemmAB<<<1536, 256, 0, stream>>>(s_bf, Wkvt, kv_bf, r_bf, Wqt, q_bf);
  k_grad<<<512, 256, 0, stream>>>(kv_bf, lr, W1tb, W2tb, W2sb, s1, s2);
  k_scan<<<256, 256, 0, stream>>>(momv, dgv, MW1, MW2, s1, s2);
  k_retr<<<1024, 512, 0, stream>>>(q_bf, s1, s2, gatep, gamma, outp);
  k_gemm1<false><<<512, 256, 0, stream>>>(outp, Wot, out, 512, 512, 4, 64);
}

// Round 13
// 169.597 us; speedup vs baseline: 1.0891x; 1.0891x over previous
//
#include <hip/hip_runtime.h>

typedef unsigned short u16;
typedef unsigned int u32;
typedef __attribute__((ext_vector_type(8))) short s16x8;
typedef __attribute__((ext_vector_type(4))) float f32x4;

#define DEV __device__ __forceinline__
#define MFMA16(a,b,c) __builtin_amdgcn_mfma_f32_16x16x32_bf16(a,b,c,0,0,0)

DEV float bf2f(u16 x){ u32 u=((u32)x)<<16; float f; __builtin_memcpy(&f,&u,4); return f; }
DEV u16 f2bf(float f){ u32 u; __builtin_memcpy(&u,&f,4); u32 r=u+0x7FFFu+((u>>16)&1u); return (u16)(r>>16); }
DEV uint4 pack8(const float* f){
  uint4 v;
  v.x=(u32)f2bf(f[0])|((u32)f2bf(f[1])<<16);
  v.y=(u32)f2bf(f[2])|((u32)f2bf(f[3])<<16);
  v.z=(u32)f2bf(f[4])|((u32)f2bf(f[5])<<16);
  v.w=(u32)f2bf(f[6])|((u32)f2bf(f[7])<<16);
  return v;
}
DEV float sigm(float x){ return 1.0f/(1.0f+__expf(-x)); }

// Fragment layout for s1/s2 (=w1c/w2c): addr(col,k) =
//   (col>>4)*2048 + (k>>5)*512 + ((k>>3)&3)*128 + (col&15)*8 + (k&7)

// ---------------------------------------------------------------------------
// act-guarded transpose tile: dst[n][k] = bf16(src[k][n]), 64x64, 256 active thr
// ---------------------------------------------------------------------------
DEV void trans_tile_a(const float* src, u16* dst, int K, int Nn, int bx, int by,
                      int tid, bool act, float* ld)
{
  int n0 = bx*64, k0 = by*64;
  if (act){
    #pragma unroll
    for (int rr=0; rr<4; rr++){
      int kk = rr*16 + (tid>>4);
      int nn = (tid&15)*4;
      float4 v = *(const float4*)(src + (size_t)(k0+kk)*Nn + n0 + nn);
      ld[kk*65+nn]=v.x; ld[kk*65+nn+1]=v.y; ld[kk*65+nn+2]=v.z; ld[kk*65+nn+3]=v.w;
    }
  }
  __syncthreads();
  if (act){
    int nn2 = tid>>2, kb = (tid&3)*16;
    float o[16];
    #pragma unroll
    for (int j=0;j<16;j++) o[j] = ld[(kb+j)*65+nn2];
    u16* dp = dst + (size_t)(n0+nn2)*K + k0 + kb;
    *(uint4*)dp     = pack8(&o[0]);
    *(uint4*)(dp+8) = pack8(&o[8]);
  }
}

// ---------------------------------------------------------------------------
// K_front: blocks [0,256) token rmsnorm + chunk gates; [256,528) weight prep.
// ---------------------------------------------------------------------------
__global__ __launch_bounds__(512) void k_front(const float* __restrict__ seq,
    const float* __restrict__ gs, const float* __restrict__ gr,
    const float* __restrict__ Wstep, const float* __restrict__ Wgate,
    const float* __restrict__ Wdec, const float* __restrict__ Wmom,
    const float* __restrict__ Wkv, const float* __restrict__ Wq,
    const float* __restrict__ Wo, const float* __restrict__ MW1,
    const float* __restrict__ MW2,
    u16* __restrict__ s, u16* __restrict__ r,
    float* __restrict__ lr, float* __restrict__ gate,
    float* __restrict__ momv, float* __restrict__ dgv,
    u16* __restrict__ Wkvt, u16* __restrict__ Wqt, u16* __restrict__ Wot,
    u16* __restrict__ W1t, u16* __restrict__ W2t, u16* __restrict__ W2s)
{
  __shared__ float smem[8192];
  const int blk = blockIdx.x;
  const int tid = threadIdx.x;

  if (blk >= 256){
    int l = blk - 256;
    bool act = tid < 256;
    int t2 = tid & 255;
    if (l < 128)      trans_tile_a(Wkv, Wkvt, 512, 1024, l&15, l>>4, t2, act, smem);
    else if (l < 192){ int m = l-128; trans_tile_a(Wq, Wqt, 512, 512, m&7, m>>3, t2, act, smem); }
    else if (l < 256){ int m = l-192; trans_tile_a(Wo, Wot, 512, 512, m&7, m>>3, t2, act, smem); }
    else if (l < 260){ int m = l-256; trans_tile_a(MW1, W1t, 128, 128, m&1, m>>1, t2, act, smem); }
    else if (l < 264){ int m = l-260; trans_tile_a(MW2, W2t, 128, 128, m&1, m>>1, t2, act, smem); }
    else {
      __syncthreads();
      if (act){
        int e = ((l-264)*256 + t2)*8;
        float f[8];
        *(float4*)&f[0] = *(const float4*)(MW2+e);
        *(float4*)&f[4] = *(const float4*)(MW2+e+4);
        *(uint4*)(W2s+e) = pack8(f);
      }
    }
    return;
  }

  float* pchunk = smem;
  float* red    = smem + 4096;
  const int b = blk >> 6, ci = blk & 63;
  const int wv = tid >> 6, lane = tid & 63;
  const size_t rowbase = (size_t)b*4096 + (size_t)ci*64;

  float psum[8] = {0,0,0,0,0,0,0,0};
  #pragma unroll 1
  for (int tt=0; tt<8; tt++){
    int t = wv*8 + tt;
    const float* row = seq + (rowbase + t)*512;
    float x[8];
    *(float4*)&x[0] = *(const float4*)(row + lane*8);
    *(float4*)&x[4] = *(const float4*)(row + lane*8 + 4);
    float ss = 0.f;
    #pragma unroll
    for (int j=0;j<8;j++) ss += x[j]*x[j];
    #pragma unroll
    for (int o=32;o>=1;o>>=1) ss += __shfl_xor(ss, o, 64);
    float inv = rsqrtf(ss*(1.0f/512.0f) + 1e-6f);
    float al[4] = {0,0,0,0}, ag[4] = {0,0,0,0};
    float sv8[8], rv8[8];
    #pragma unroll
    for (int j=0;j<8;j++){
      int d = lane*8 + j;
      float sn = x[j]*inv;
      float sv = sn*gs[d];
      float rv = sn*gr[d];
      sv8[j]=sv; rv8[j]=rv;
      psum[j] += sv;
      float4 wst = *(const float4*)(Wstep + d*4);
      float4 wgt = *(const float4*)(Wgate + d*4);
      al[0]+=sv*wst.x; al[1]+=sv*wst.y; al[2]+=sv*wst.z; al[3]+=sv*wst.w;
      ag[0]+=rv*wgt.x; ag[1]+=rv*wgt.y; ag[2]+=rv*wgt.z; ag[3]+=rv*wgt.w;
    }
    *(uint4*)(s + (rowbase+t)*512 + lane*8) = pack8(sv8);
    *(uint4*)(r + (rowbase+t)*512 + lane*8) = pack8(rv8);
    #pragma unroll
    for (int o=32;o>=1;o>>=1){
      #pragma unroll
      for (int h=0;h<4;h++){ al[h] += __shfl_xor(al[h], o, 64); ag[h] += __shfl_xor(ag[h], o, 64); }
    }
    if (lane == 0){
      #pragma unroll
      for (int h=0;h<4;h++){
        lr[(rowbase+t)*4 + h]   = sigm(al[h]);
        gate[(rowbase+t)*4 + h] = sigm(ag[h]);
      }
    }
  }
  #pragma unroll
  for (int j=0;j<8;j++) pchunk[wv*512 + lane*8+j] = psum[j];
  __syncthreads();
  {
    int d = tid;
    float mean = 0.f;
    #pragma unroll
    for (int w=0;w<8;w++) mean += pchunk[w*512 + d];
    mean *= (1.0f/64.0f);
    #pragma unroll
    for (int h=0;h<4;h++){
      red[h*512 + d]     = mean*Wdec[d*4+h];
      red[(4+h)*512 + d] = mean*Wmom[d*4+h];
    }
  }
  __syncthreads();
  {
    float sum = 0.f;
    #pragma unroll
    for (int j=0;j<8;j++) sum += red[wv*512 + lane*8+j];
    #pragma unroll
    for (int o=32;o>=1;o>>=1) sum += __shfl_xor(sum, o, 64);
    if (lane == 0){
      if (wv < 4) dgv[((size_t)(b*4+wv))*64 + ci]      = 1.0f - sigm(sum);
      else        momv[((size_t)(b*4+(wv-4)))*64 + ci] = sigm(sum);
    }
  }
}

// ---------------------------------------------------------------------------
// GEMM tile body (m97 structure).
// ---------------------------------------------------------------------------
template<bool OUT_BF>
DEV void gemm_body(const u16* A, const u16* Bt, void* Cv, int K, int ldc,
                   int bx, int by, u16* sA, u16* sB)
{
  const int tid = threadIdx.x;
  const int wv = tid>>6, lane = tid&63, lrow = lane&15, lk = lane>>4;
  const int wm = (wv>>1)*64, wn = (wv&1)*64;
  const int rowbase = by*128, colbase = bx*128;
  const int srow = lane>>3;
  const int scol = (lane&7)*8;
  f32x4 acc[4][4] = {};
  for (int kc = 0; kc < K; kc += 64){
    __syncthreads();
    #pragma unroll
    for (int it=0; it<4; ++it){
      int seg = it*4 + wv;
      int row = seg*8 + srow;
      __builtin_amdgcn_global_load_lds(
        (const __attribute__((address_space(1))) void*)(A + (size_t)(rowbase+row)*K + kc + scol),
        (__attribute__((address_space(3))) void*)&sA[seg*512 + lane*8], 16, 0, 0);
      __builtin_amdgcn_global_load_lds(
        (const __attribute__((address_space(1))) void*)(Bt + (size_t)(colbase+row)*K + kc + scol),
        (__attribute__((address_space(3))) void*)&sB[seg*512 + lane*8], 16, 0, 0);
    }
    __syncthreads();
    #pragma unroll
    for (int k0=0;k0<2;k0++){
      s16x8 a[4], b[4];
      #pragma unroll
      for (int m=0;m<4;m++) a[m] = *(const s16x8*)&sA[(wm+m*16+lrow)*64 + k0*32 + lk*8];
      #pragma unroll
      for (int n=0;n<4;n++) b[n] = *(const s16x8*)&sB[(wn+n*16+lrow)*64 + k0*32 + lk*8];
      #pragma unroll
      for (int m=0;m<4;m++)
        #pragma unroll
        for (int n=0;n<4;n++)
          acc[m][n] = MFMA16(a[m], b[n], acc[m][n]);
    }
  }
  #pragma unroll
  for (int m=0;m<4;m++)
    #pragma unroll
    for (int n=0;n<4;n++)
      #pragma unroll
      for (int r=0;r<4;r++){
        int row = rowbase + wm + m*16 + lk*4 + r;
        int col = colbase + wn + n*16 + lrow;
        float v = acc[m][n][r];
        if (OUT_BF) ((u16*)Cv)[(size_t)row*ldc + col] = f2bf(v);
        else        ((float*)Cv)[(size_t)row*ldc + col] = v;
      }
}

// merged kv + q GEMM
__global__ __launch_bounds__(256) void k_gemmAB(const u16* __restrict__ A1,
    const u16* __restrict__ B1, u16* __restrict__ C1,
    const u16* __restrict__ A2, const u16* __restrict__ B2, u16* __restrict__ C2)
{
  __shared__ u16 sA[128*64];
  __shared__ u16 sB[128*64];
  int bid = blockIdx.x;
  if (bid < 1024){
    int s = (bid & 7)*128 + (bid >> 3);
    gemm_body<true>(A1, B1, C1, 512, 1024, s & 7, s >> 3, sA, sB);
  } else {
    int l = bid - 1024;
    int s = (l & 7)*64 + (l >> 3);
    gemm_body<true>(A2, B2, C2, 512, 512, s & 3, s >> 2, sA, sB);
  }
}

// single GEMM (out-projection)
template<bool OUT_BF>
__global__ __launch_bounds__(256) void k_gemm1(const u16* __restrict__ A,
    const u16* __restrict__ Bt, void* __restrict__ Cv, int K, int ldc, int nbx, int cpx)
{
  __shared__ u16 sA[128*64];
  __shared__ u16 sB[128*64];
  int bid = blockIdx.x;
  int s = (bid & 7)*cpx + (bid >> 3);
  gemm_body<OUT_BF>(A, Bt, Cv, K, ldc, s % nbx, s / nbx, sA, sB);
}

// ---------------------------------------------------------------------------
// K4: per-chunk gradient (round-11 best). s1/s2 in fragment layout.
// v staged coalesced into bufPt at stage0; vv read from LDS in mm2.
// ---------------------------------------------------------------------------
__global__ __launch_bounds__(256,4) void k_grad(const u16* __restrict__ kv,
    const float* __restrict__ lr, const u16* __restrict__ W1t,
    const u16* __restrict__ W2t, const u16* __restrict__ W2s,
    u16* __restrict__ s1, u16* __restrict__ s2)
{
  __shared__ u16 bufR[64*136];   // kc -> As -> dP -> dHt([128][68] view)
  __shared__ u16 bufAt[128*68];  // Ast
  __shared__ u16 bufPt[128*68];  // v ([64][136] view) -> dPt
  __shared__ float lrs[64];

  const int blk = blockIdx.x;
  const int bhi = blk >> 6, ci = blk & 63;
  const int b = bhi >> 2, hd = bhi & 3;
  const int tid = threadIdx.x;
  const int wv = tid>>6, lane = tid&63, lrow = lane&15, lk = lane>>4;
  int col[2]; col[0] = wv*32 + lrow; col[1] = wv*32 + 16 + lrow;
  const int f_hi[2] = { (lrow>>3)*128, ((16+lrow)>>3)*128 };
  const int f_lo[2] = { lrow&7, (16+lrow)&7 };
  const int fbase = wv*512;
  const size_t rowbase = (size_t)b*4096 + (size_t)ci*64;
  const u16* kvb = kv + rowbase*1024 + hd*128;

  // stage0: kc rows -> bufR, v rows -> bufPt ([64][136] view), both coalesced
  #pragma unroll
  for (int rep=0;rep<4;rep++){
    int lin = rep*2048 + tid*8;
    int i = lin >> 7, d = lin & 127;
    *(uint4*)&bufR[i*136 + d]  = *(const uint4*)(kvb + (size_t)i*1024 + d);
    *(uint4*)&bufPt[i*136 + d] = *(const uint4*)(kvb + (size_t)i*1024 + 512 + d);
  }
  if (tid < 64) lrs[tid] = lr[(rowbase + tid)*4 + hd] * (2.0f/128.0f);
  __syncthreads();

  float spv[4][2][4];

  // mm1
  {
    f32x4 acc[4][2] = {};
    #pragma unroll
    for (int k0=0;k0<4;k0++){
      s16x8 w0 = *(const s16x8*)(W1t + col[0]*128 + k0*32 + lk*8);
      s16x8 w1 = *(const s16x8*)(W1t + col[1]*128 + k0*32 + lk*8);
      #pragma unroll
      for (int m=0;m<4;m++){
        s16x8 a = *(const s16x8*)&bufR[(m*16+lrow)*136 + k0*32 + lk*8];
        acc[m][0] = MFMA16(a, w0, acc[m][0]);
        acc[m][1] = MFMA16(a, w1, acc[m][1]);
      }
    }
    __syncthreads();
    #pragma unroll
    for (int m=0;m<4;m++)
      #pragma unroll
      for (int n=0;n<2;n++){
        int row0 = m*16 + lk*4;
        u16 av4[4];
        #pragma unroll
        for (int r=0;r<4;r++){
          float h = acc[m][n][r];
          float sg = sigm(h);
          av4[r] = f2bf(h*sg);
          spv[m][n][r] = sg*(1.0f + h*(1.0f - sg));
          bufR[(row0+r)*136 + col[n]] = av4[r];
        }
        *(uint2*)&bufAt[col[n]*68 + row0] = make_uint2(
          (u32)av4[0] | ((u32)av4[1]<<16), (u32)av4[2] | ((u32)av4[3]<<16));
      }
  }
  __syncthreads();

  // mm2: P = A @ W2 ; dP = lr*(P - v)   (v from LDS bufPt)
  {
    f32x4 acc[4][2] = {};
    #pragma unroll
    for (int k0=0;k0<4;k0++){
      s16x8 w0 = *(const s16x8*)(W2t + col[0]*128 + k0*32 + lk*8);
      s16x8 w1 = *(const s16x8*)(W2t + col[1]*128 + k0*32 + lk*8);
      #pragma unroll
      for (int m=0;m<4;m++){
        s16x8 a = *(const s16x8*)&bufR[(m*16+lrow)*136 + k0*32 + lk*8];
        acc[m][0] = MFMA16(a, w0, acc[m][0]);
        acc[m][1] = MFMA16(a, w1, acc[m][1]);
      }
    }
    u16 vv[4][2][4];
    #pragma unroll
    for (int m=0;m<4;m++)
      #pragma unroll
      for (int n=0;n<2;n++)
        #pragma unroll
        for (int r=0;r<4;r++)
          vv[m][n][r] = bufPt[(m*16+lk*4+r)*136 + col[n]];
    __syncthreads();   // As reads + v reads complete before overwrites
    #pragma unroll
    for (int m=0;m<4;m++)
      #pragma unroll
      for (int n=0;n<2;n++){
        int row0 = m*16 + lk*4;
        u16 dp4[4];
        #pragma unroll
        for (int r=0;r<4;r++){
          float dp = lrs[row0+r]*(acc[m][n][r] - bf2f(vv[m][n][r]));
          dp4[r] = f2bf(dp);
          bufR[(row0+r)*136 + col[n]] = dp4[r];
        }
        *(uint2*)&bufPt[col[n]*68 + row0] = make_uint2(
          (u32)dp4[0] | ((u32)dp4[1]<<16), (u32)dp4[2] | ((u32)dp4[3]<<16));
      }
  }
  __syncthreads();

  // mm3: dA = dP @ W2^T ; dHt -> bufR
  {
    f32x4 da[4][2] = {};
    #pragma unroll
    for (int k0=0;k0<4;k0++){
      s16x8 w0 = *(const s16x8*)(W2s + col[0]*128 + k0*32 + lk*8);
      s16x8 w1 = *(const s16x8*)(W2s + col[1]*128 + k0*32 + lk*8);
      #pragma unroll
      for (int m=0;m<4;m++){
        s16x8 a = *(const s16x8*)&bufR[(m*16+lrow)*136 + k0*32 + lk*8];
        da[m][0] = MFMA16(a, w0, da[m][0]);
        da[m][1] = MFMA16(a, w1, da[m][1]);
      }
    }
    __syncthreads();
    #pragma unroll
    for (int m=0;m<4;m++)
      #pragma unroll
      for (int n=0;n<2;n++){
        int row0 = m*16 + lk*4;
        u16 dh4[4];
        #pragma unroll
        for (int r=0;r<4;r++) dh4[r] = f2bf(spv[m][n][r]*da[m][n][r]);
        *(uint2*)&bufR[col[n]*68 + row0] = make_uint2(
          (u32)dh4[0] | ((u32)dh4[1]<<16), (u32)dh4[2] | ((u32)dh4[3]<<16));
      }
  }

  const size_t outbase = (size_t)blk * 16384;

  // mm4 + kct gather (late, from global - L2-hot, short register lifetime)
  s16x8 kbf[2][2];
  #pragma unroll
  for (int n=0;n<2;n++)
    #pragma unroll
    for (int k0=0;k0<2;k0++)
      #pragma unroll
      for (int j=0;j<8;j++)
        ((u16*)&kbf[n][k0])[j] = kvb[(size_t)(k0*32 + lk*8 + j)*1024 + col[n]];
  {
    f32x4 acc[8][2] = {};
    #pragma unroll
    for (int k0=0;k0<2;k0++){
      s16x8 bf0 = *(const s16x8*)&bufAt[col[0]*68 + k0*32 + lk*8];
      s16x8 bf1 = *(const s16x8*)&bufAt[col[1]*68 + k0*32 + lk*8];
      #pragma unroll
      for (int m=0;m<8;m++){
        s16x8 a = *(const s16x8*)&bufPt[(m*16+lrow)*68 + k0*32 + lk*8];
        acc[m][0] = MFMA16(a, bf0, acc[m][0]);
        acc[m][1] = MFMA16(a, bf1, acc[m][1]);
      }
    }
    #pragma unroll
    for (int m=0;m<8;m++)
      #pragma unroll
      for (int n=0;n<2;n++)
        #pragma unroll
        for (int r=0;r<4;r++)
          s2[outbase + m*2048 + fbase + f_hi[n] + (lk*4+r)*8 + f_lo[n]] = f2bf(-acc[m][n][r]);
  }
  __syncthreads();

  // mm5: s1t = -(dHt x kct)
  {
    f32x4 acc[8][2] = {};
    #pragma unroll
    for (int k0=0;k0<2;k0++)
      #pragma unroll
      for (int m=0;m<8;m++){
        s16x8 a = *(const s16x8*)&bufR[(m*16+lrow)*68 + k0*32 + lk*8];
        acc[m][0] = MFMA16(a, kbf[0][k0], acc[m][0]);
        acc[m][1] = MFMA16(a, kbf[1][k0], acc[m][1]);
      }
    #pragma unroll
    for (int m=0;m<8;m++)
      #pragma unroll
      for (int n=0;n<2;n++)
        #pragma unroll
        for (int r=0;r<4;r++)
          s1[outbase + m*2048 + fbase + f_hi[n] + (lk*4+r)*8 + f_lo[n]] = f2bf(-acc[m][n][r]);
  }
}

// ---------------------------------------------------------------------------
// K5: fused momentum + decay scans, 4 elems/thread (uint2 per array), unroll 4.
// ---------------------------------------------------------------------------
__global__ __launch_bounds__(256) void k_scan(const float* __restrict__ momv,
    const float* __restrict__ dgv, const float* __restrict__ MW1,
    const float* __restrict__ MW2, u16* __restrict__ s1w, u16* __restrict__ s2w)
{
  int bhi = blockIdx.x >> 4, eb = blockIdx.x & 15;
  int e0 = eb*1024 + threadIdx.x*4;
  int colD = ((e0>>11)<<4) + ((e0>>3)&15);
  int kD   = ((e0>>9)&3)*32 + ((e0>>7)&3)*8 + (e0&7);
  float u1[4], u2[4], m1[4]={0,0,0,0}, m2[4]={0,0,0,0};
  #pragma unroll
  for (int j=0;j<4;j++){
    u1[j] = MW1[(kD+j)*128 + colD];
    u2[j] = MW2[(kD+j)*128 + colD];
  }
  size_t base = (size_t)bhi*64*16384 + e0;
  const float* mv = momv + bhi*64;
  const float* dv = dgv + bhi*64;
  #pragma unroll 4
  for (int t=0; t<64; t++){
    float g  = mv[t];
    float dg = dv[t];
    size_t idx = base + (size_t)t*16384;
    uint2 a = *(const uint2*)(s1w + idx);
    uint2 c = *(const uint2*)(s2w + idx);
    uint2 w1o, w2o;
    w1o.x = (u32)f2bf(u1[0]) | ((u32)f2bf(u1[1])<<16);
    w1o.y = (u32)f2bf(u1[2]) | ((u32)f2bf(u1[3])<<16);
    w2o.x = (u32)f2bf(u2[0]) | ((u32)f2bf(u2[1])<<16);
    w2o.y = (u32)f2bf(u2[2]) | ((u32)f2bf(u2[3])<<16);
    *(uint2*)(s1w + idx) = w1o;
    *(uint2*)(s2w + idx) = w2o;
    u16 ah[4] = {(u16)(a.x&0xffffu),(u16)(a.x>>16),(u16)(a.y&0xffffu),(u16)(a.y>>16)};
    u16 ch[4] = {(u16)(c.x&0xffffu),(u16)(c.x>>16),(u16)(c.y&0xffffu),(u16)(c.y>>16)};
    #pragma unroll
    for (int j=0;j<4;j++){
      m1[j] = g*m1[j] + bf2f(ah[j]);
      m2[j] = g*m2[j] + bf2f(ch[j]);
      u1[j] = dg*u1[j] + m1[j];
      u2[j] = dg*u2[j] + m2[j];
    }
  }
}

// ---------------------------------------------------------------------------
// K6: retrieval. q staged via LDS; w1c/w2c coalesced fragment-order loads.
// ---------------------------------------------------------------------------
__global__ __launch_bounds__(512) void k_retr(const u16* __restrict__ qin,
    const u16* __restrict__ w1c, const u16* __restrict__ w2c,
    const float* __restrict__ gate, const float* __restrict__ gamma,
    u16* __restrict__ outp)
{
  __shared__ u16 bufQ[64*136];
  __shared__ u16 bufA[64*132];
  __shared__ float rsum[8][64];
  const int blk = blockIdx.x;
  const int bhi = blk >> 6, ci = blk & 63;
  const int b = bhi >> 2, hd = bhi & 3;
  const int tid = threadIdx.x;
  const int wv = tid>>6, lane = tid&63, lrow = lane&15, lk = lane>>4;
  const int colw = wv*16 + lrow;
  const size_t rowbase = (size_t)b*4096 + (size_t)ci*64;
  const u16* w1 = w1c + (size_t)blk*16384;
  const u16* w2 = w2c + (size_t)blk*16384;
  const int lane8 = lane*8;

  #pragma unroll
  for (int rep=0;rep<2;rep++){
    int lin = rep*4096 + tid*8;
    int i = lin>>7, d = lin&127;
    *(uint4*)&bufQ[i*136 + d] = *(const uint4*)(qin + (rowbase+i)*512 + hd*128 + d);
  }
  __syncthreads();

  // mm1: Hq = q @ w1 ; A = silu
  {
    s16x8 wf[4];
    #pragma unroll
    for (int k0=0;k0<4;k0++) wf[k0] = *(const s16x8*)(w1 + wv*2048 + k0*512 + lane8);
    f32x4 acc[4] = {};
    #pragma unroll
    for (int k0=0;k0<4;k0++){
      #pragma unroll
      for (int m=0;m<4;m++){
        s16x8 a = *(const s16x8*)&bufQ[(m*16+lrow)*136 + k0*32 + lk*8];
        acc[m] = MFMA16(a, wf[k0], acc[m]);
      }
    }
    #pragma unroll
    for (int m=0;m<4;m++){
      #pragma unroll
      for (int r=0;r<4;r++){
        float h = acc[m][r];
        bufA[(m*16+lk*4+r)*132 + colw] = f2bf(h*sigm(h));
      }
    }
  }
  __syncthreads();

  // mm2: P = A @ w2
  f32x4 acc[4] = {};
  {
    s16x8 wf[4];
    #pragma unroll
    for (int k0=0;k0<4;k0++) wf[k0] = *(const s16x8*)(w2 + wv*2048 + k0*512 + lane8);
    #pragma unroll
    for (int k0=0;k0<4;k0++){
      #pragma unroll
      for (int m=0;m<4;m++){
        s16x8 a = *(const s16x8*)&bufA[(m*16+lrow)*132 + k0*32 + lk*8];
        acc[m] = MFMA16(a, wf[k0], acc[m]);
      }
    }
  }
  #pragma unroll
  for (int m=0;m<4;m++){
    #pragma unroll
    for (int r=0;r<4;r++){
      float p = acc[m][r]*acc[m][r];
      p += __shfl_xor(p, 1, 64);
      p += __shfl_xor(p, 2, 64);
      p += __shfl_xor(p, 4, 64);
      p += __shfl_xor(p, 8, 64);
      if (lrow == 0) rsum[wv][m*16 + lk*4 + r] = p;
    }
  }
  __syncthreads();
  float gm = gamma[hd*128 + colw] + 1.0f;
  #pragma unroll
  for (int m=0;m<4;m++){
    #pragma unroll
    for (int r=0;r<4;r++){
      int row = m*16 + lk*4 + r;
      float sum = rsum[0][row]+rsum[1][row]+rsum[2][row]+rsum[3][row]
                + rsum[4][row]+rsum[5][row]+rsum[6][row]+rsum[7][row];
      float inv = rsqrtf(sum*(1.0f/128.0f) + 1e-6f);
      float gt = gate[(rowbase+row)*4 + hd];
      outp[(rowbase+row)*512 + hd*128 + colw] = f2bf(acc[m][r]*inv*gm*gt);
    }
  }
}

// ---------------------------------------------------------------------------
extern "C" void kernel_launch(void* const* d_in, const int* in_sizes, int n_in,
                              void* d_out, int out_size, void* d_ws, size_t ws_size,
                              hipStream_t stream)
{
  const float* seq    = (const float*)d_in[0];
  const float* gstore = (const float*)d_in[1];
  const float* gret   = (const float*)d_in[2];
  const float* W_q    = (const float*)d_in[3];
  const float* W_kv   = (const float*)d_in[4];
  const float* W_step = (const float*)d_in[5];
  const float* W_mom  = (const float*)d_in[6];
  const float* W_dec  = (const float*)d_in[7];
  const float* W_gate = (const float*)d_in[8];
  const float* gamma  = (const float*)d_in[9];
  const float* W_o    = (const float*)d_in[10];
  const float* MW1    = (const float*)d_in[11];
  const float* MW2    = (const float*)d_in[12];
  float* out = (float*)d_out;

  const size_t NS = (size_t)16384*512;
  const size_t NG = (size_t)16*64*16384;
  size_t need = (5*NS + 2*NG + 524288 + 262144 + 262144 + 3*16384)*2
              + (2*65536 + 2048)*4;
  if (ws_size < need) return;

  char* ws = (char*)d_ws;
  u16* s_bf = (u16*)ws; ws += NS*2;        // s; reused as outp
  u16* r_bf = (u16*)ws; ws += NS*2;
  u16* kv_bf= (u16*)ws; ws += 2*NS*2;
  u16* q_bf = (u16*)ws; ws += NS*2;
  u16* s1   = (u16*)ws; ws += NG*2;        // -> w1c after k_scan
  u16* s2   = (u16*)ws; ws += NG*2;        // -> w2c
  u16* Wkvt = (u16*)ws; ws += (size_t)524288*2;
  u16* Wqt  = (u16*)ws; ws += (size_t)262144*2;
  u16* Wot  = (u16*)ws; ws += (size_t)262144*2;
  u16* W1tb = (u16*)ws; ws += (size_t)16384*2;
  u16* W2tb = (u16*)ws; ws += (size_t)16384*2;
  u16* W2sb = (u16*)ws; ws += (size_t)16384*2;
  float* lr   = (float*)ws; ws += (size_t)65536*4;
  float* gatep= (float*)ws; ws += (size_t)65536*4;
  float* momv = (float*)ws; ws += 1024*4;
  float* dgv  = (float*)ws; ws += 1024*4;
  u16* outp = s_bf;

  k_front<<<528, 512, 0, stream>>>(seq, gstore, gret, W_step, W_gate, W_dec, W_mom,
                                   W_kv, W_q, W_o, MW1, MW2,
                                   s_bf, r_bf, lr, gatep, momv, dgv,
                                   Wkvt, Wqt, Wot, W1tb, W2tb, W2sb);
  k_gemmAB<<<1536, 256, 0, stream>>>(s_bf, Wkvt, kv_bf, r_bf, Wqt, q_bf);
  k_grad<<<1024, 256, 0, stream>>>(kv_bf, lr, W1tb, W2tb, W2sb, s1, s2);
  k_scan<<<256, 256, 0, stream>>>(momv, dgv, MW1, MW2, s1, s2);
  k_retr<<<1024, 512, 0, stream>>>(q_bf, s1, s2, gatep, gamma, outp);
  k_gemm1<false><<<512, 256, 0, stream>>>(outp, Wot, out, 512, 512, 4, 64);
}